// Round 2
// baseline (2524.770 us; speedup 1.0000x reference)
//
#include <hip/hip_runtime.h>
#include <math.h>

#define P 512
#define KC 10
#define NB 32
#define EPSV 0.01f

// ---------------- metadata kernels ----------------

__global__ __launch_bounds__(64) void meta_zero(int* counts, int* cursors){
  int t = threadIdx.x;
  if (t < KC){ counts[t] = 0; cursors[t] = 0; }
}

__global__ __launch_bounds__(256) void hist_k(const int* __restrict__ Y, int* counts, int m){
  int i = blockIdx.x * 256 + threadIdx.x;
  if (i < m){
    int y = Y[i];
    if (y >= 0 && y < KC) atomicAdd(&counts[y], 1);
  }
}

__global__ __launch_bounds__(64) void offsets_k(const int* __restrict__ counts, int* offsets){
  if (threadIdx.x == 0){
    int s = 0;
    for (int j = 0; j < KC; ++j){ offsets[j] = s; s += counts[j]; }
    offsets[KC] = s;
  }
}

__global__ __launch_bounds__(256) void scatter_k(const int* __restrict__ Y, const int* __restrict__ offsets,
                                                 int* cursors, int* __restrict__ perm, int m){
  int i = blockIdx.x * 256 + threadIdx.x;
  if (i < m){
    int y = Y[i];
    if (y >= 0 && y < KC){
      int pos = offsets[y] + atomicAdd(&cursors[y], 1);
      perm[pos] = i;
    }
  }
}

// ---------------- per-class Gram (lower-triangle 64x64 tiles) ----------------
// grid: (36, KC). Block 256 = 16x16 threads, 4x4 outputs/thread.
__global__ __launch_bounds__(256) void gram_k(const float* __restrict__ X,
                                              const int* __restrict__ perm,
                                              const int* __restrict__ offsets,
                                              float* __restrict__ Gk){
  __shared__ float As[16][64];
  __shared__ float Bs[16][64];

  int cls = blockIdx.y;
  int ta = 0, rem = blockIdx.x;
  while (rem >= ta + 1){ rem -= ta + 1; ++ta; }
  int tb = rem;
  int a0 = ta * 64, b0 = tb * 64;
  bool diag = (ta == tb);

  int start = offsets[cls];
  int n = offsets[cls + 1] - start;

  int tid = threadIdx.x;
  int tx = tid & 15, ty = tid >> 4;

  float acc[4][4];
  #pragma unroll
  for (int i = 0; i < 4; ++i)
    #pragma unroll
    for (int j = 0; j < 4; ++j) acc[i][j] = 0.f;

  int c = tid & 63;
  int kb = tid >> 6;   // 0..3

  for (int r0 = 0; r0 < n; r0 += 16){
    #pragma unroll
    for (int it = 0; it < 4; ++it){
      int kk = it * 4 + kb;
      int r = r0 + kk;
      float va = 0.f, vb = 0.f;
      if (r < n){
        int row = perm[start + r];
        const float* xp = X + (long)row * P;
        va = xp[a0 + c];
        if (!diag) vb = xp[b0 + c];
      }
      As[kk][c] = va;
      if (!diag) Bs[kk][c] = vb;
    }
    __syncthreads();
    const float (*Bp)[64] = diag ? As : Bs;
    #pragma unroll
    for (int kk = 0; kk < 16; ++kk){
      float4 a4 = *(const float4*)&As[kk][ty * 4];
      float4 b4 = *(const float4*)&Bp[kk][tx * 4];
      float av[4] = {a4.x, a4.y, a4.z, a4.w};
      float bv[4] = {b4.x, b4.y, b4.z, b4.w};
      #pragma unroll
      for (int i = 0; i < 4; ++i)
        #pragma unroll
        for (int j = 0; j < 4; ++j)
          acc[i][j] += av[i] * bv[j];
    }
    __syncthreads();
  }

  float* C = Gk + (long)cls * P * P;
  #pragma unroll
  for (int i = 0; i < 4; ++i){
    int a = a0 + ty * 4 + i;
    #pragma unroll
    for (int j = 0; j < 4; ++j){
      int b = b0 + tx * 4 + j;
      C[a * P + b] = acc[i][j];
    }
  }
}

// ---------------- form A_j = I + s_j*Gk_j (in place, lower tri); slot 10 = I + scal*sum ----------------
__global__ __launch_bounds__(256) void formA_k(float* __restrict__ Gk, const int* __restrict__ counts, float m_tot){
  int idx = blockIdx.x * 256 + threadIdx.x;
  int r = idx >> 9, cc = idx & (P - 1);
  if (cc > r) return;
  long off = (long)r * P + cc;
  float diag = (r == cc) ? 1.f : 0.f;
  float g = 0.f;
  #pragma unroll
  for (int j = 0; j < KC; ++j){
    float v = Gk[(long)j * P * P + off];
    g += v;
    float trPi = (float)counts[j] + 1e-8f;
    float s = (float)P / (trPi * EPSV);
    Gk[(long)j * P * P + off] = diag + s * v;
  }
  float scal = (float)P / (m_tot * EPSV);
  Gk[(long)KC * P * P + off] = diag + scal * g;
}

// ---------------- batched blocked Cholesky logdet ----------------
// Right-looking panel factorization held in REGISTERS (2 rows/thread), one
// barrier per column via a per-column LDS broadcast slab. Trailing syrk from
// XOR-swizzled LDS panel (conflict-free), 8x8 register tiles.
__global__ __launch_bounds__(256) void chol_k(float* __restrict__ Amats, float* __restrict__ logdets){
  __shared__ float Lp[NB * P];      // 64 KiB: swizzled panel rows (for syrk)
  __shared__ float prbuf[NB * NB];  // 4 KiB: pivot-block broadcast, one row per column
  float* A = Amats + (long)blockIdx.x * P * P;
  int tid = threadIdx.x;
  float logsum = 0.f;

  for (int j0 = 0; j0 < P; j0 += NB){
    int q = P - j0;
    int i1 = j0 + tid;
    int i2 = i1 + 256;
    bool has1 = (tid < q);
    bool has2 = (tid + 256 < q);
    float a1[NB], a2[NB];

    if (has1){
      const float* src = A + (long)i1 * P + j0;
      #pragma unroll
      for (int u = 0; u < NB; u += 4){
        float4 v = *(const float4*)(src + u);
        a1[u] = v.x; a1[u+1] = v.y; a1[u+2] = v.z; a1[u+3] = v.w;
      }
    }
    if (has2){
      const float* src = A + (long)i2 * P + j0;
      #pragma unroll
      for (int u = 0; u < NB; u += 4){
        float4 v = *(const float4*)(src + u);
        a2[u] = v.x; a2[u+1] = v.y; a2[u+2] = v.z; a2[u+3] = v.w;
      }
    }

    // ---- factor panel: right-looking, registers only, 1 barrier/column ----
    #pragma unroll
    for (int jj = 0; jj < NB; ++jj){
      if (tid < NB) prbuf[jj * NB + tid] = a1[jj];   // diag-block rows broadcast col jj
      __syncthreads();
      float pr[NB];
      #pragma unroll
      for (int u = 0; u < NB; u += 4){
        float4 v = *(const float4*)&prbuf[jj * NB + u];
        pr[u] = v.x; pr[u+1] = v.y; pr[u+2] = v.z; pr[u+3] = v.w;
      }
      float d = pr[jj];
      if (tid == 0) logsum += logf(d);
      float inv = 1.0f / d;
      float rs = rsqrtf(d);
      if (has1 && tid >= jj){
        float w = a1[jj] * inv;
        #pragma unroll
        for (int l = 0; l < NB; ++l) if (l > jj) a1[l] -= w * pr[l];
        a1[jj] *= rs;
      }
      if (has2){
        float w = a2[jj] * inv;
        #pragma unroll
        for (int l = 0; l < NB; ++l) if (l > jj) a2[l] -= w * pr[l];
        a2[jj] *= rs;
      }
    }

    int j1 = j0 + NB;
    if (j1 < P){
      // stage rows >= j1 into swizzled LDS for syrk
      if (has1 && tid >= NB){
        #pragma unroll
        for (int u = 0; u < NB; ++u) Lp[i1 * NB + (u ^ (i1 & 31))] = a1[u];
      }
      if (has2){
        #pragma unroll
        for (int u = 0; u < NB; ++u) Lp[i2 * NB + (u ^ (i2 & 31))] = a2[u];
      }
      __syncthreads();

      // trailing update: A[i][l] -= sum_u L[i][u]*L[l][u], i,l >= j1, l <= i
      int tx = tid & 15, ty = tid >> 4;
      for (int ti0 = j1; ti0 < P; ti0 += 128){
        for (int tl0 = j1; tl0 <= ti0; tl0 += 128){
          float accC[8][8];
          #pragma unroll
          for (int r = 0; r < 8; ++r)
            #pragma unroll
            for (int c2 = 0; c2 < 8; ++c2) accC[r][c2] = 0.f;

          for (int u = 0; u < NB; ++u){
            float a8[8], b8[8];
            #pragma unroll
            for (int r = 0; r < 8; ++r){
              int i = ti0 + ty + 16 * r;
              a8[r] = (i < P) ? Lp[i * NB + (u ^ (i & 31))] : 0.f;
            }
            #pragma unroll
            for (int c2 = 0; c2 < 8; ++c2){
              int l = tl0 + tx + 16 * c2;
              b8[c2] = (l < P) ? Lp[l * NB + (u ^ (l & 31))] : 0.f;
            }
            #pragma unroll
            for (int r = 0; r < 8; ++r)
              #pragma unroll
              for (int c2 = 0; c2 < 8; ++c2)
                accC[r][c2] += a8[r] * b8[c2];
          }

          #pragma unroll
          for (int r = 0; r < 8; ++r){
            int i = ti0 + ty + 16 * r;
            if (i >= P) continue;
            #pragma unroll
            for (int c2 = 0; c2 < 8; ++c2){
              int l = tl0 + tx + 16 * c2;
              if (l < P && l <= i)
                A[(long)i * P + l] -= accC[r][c2];
            }
          }
        }
      }
      __syncthreads();   // syrk global writes visible before next panel load; Lp reuse
    }
  }

  if (tid == 0) logdets[blockIdx.x] = logsum;
}

// ---------------- final reduction ----------------
__global__ __launch_bounds__(64) void final_k(const float* __restrict__ logdets,
                                              const int* __restrict__ counts,
                                              float* __restrict__ out, float m_tot){
  if (threadIdx.x == 0 && blockIdx.x == 0){
    out[0] = 0.5f * logdets[KC];
    float comp = 0.f;
    for (int j = 0; j < KC; ++j){
      float trPi = (float)counts[j] + 1e-8f;
      comp += logdets[j] * trPi / m_tot;
    }
    out[1] = 0.5f * comp;
  }
}

extern "C" void kernel_launch(void* const* d_in, const int* in_sizes, int n_in,
                              void* d_out, int out_size, void* d_ws, size_t ws_size,
                              hipStream_t stream) {
  (void)n_in; (void)out_size; (void)ws_size;
  const float* X = (const float*)d_in[0];
  const int*   Y = (const int*)d_in[1];
  int m = in_sizes[0] / P;     // 16384

  float* Gk      = (float*)d_ws;                 // 11 * P*P floats
  int*   perm    = (int*)(Gk + 11L * P * P);     // m ints
  int*   counts  = perm + m;                     // 16
  int*   cursors = counts + 16;                  // 16
  int*   offsets = cursors + 16;                 // 16
  float* logdets = (float*)(offsets + 16);       // 11

  meta_zero<<<1, 64, 0, stream>>>(counts, cursors);
  hist_k<<<(m + 255) / 256, 256, 0, stream>>>(Y, counts, m);
  offsets_k<<<1, 64, 0, stream>>>(counts, offsets);
  scatter_k<<<(m + 255) / 256, 256, 0, stream>>>(Y, offsets, cursors, perm, m);

  dim3 gg(36, KC);
  gram_k<<<gg, 256, 0, stream>>>(X, perm, offsets, Gk);

  formA_k<<<(P * P) / 256, 256, 0, stream>>>(Gk, counts, (float)m);

  chol_k<<<KC + 1, 256, 0, stream>>>(Gk, logdets);

  final_k<<<1, 64, 0, stream>>>(logdets, counts, (float*)d_out, (float)m);
}

// Round 3
// 1816.180 us; speedup vs baseline: 1.3902x; 1.3902x over previous
//
#include <hip/hip_runtime.h>
#include <math.h>

#define P 512
#define KC 10
#define NB 32
#define EPSV 0.01f

// ---------------- metadata kernels ----------------

__global__ __launch_bounds__(64) void meta_zero(int* counts, int* cursors, float* logdets){
  int t = threadIdx.x;
  if (t < KC){ counts[t] = 0; cursors[t] = 0; }
  if (t < KC + 1) logdets[t] = 0.f;
}

__global__ __launch_bounds__(256) void hist_k(const int* __restrict__ Y, int* counts, int m){
  int i = blockIdx.x * 256 + threadIdx.x;
  if (i < m){
    int y = Y[i];
    if (y >= 0 && y < KC) atomicAdd(&counts[y], 1);
  }
}

__global__ __launch_bounds__(64) void offsets_k(const int* __restrict__ counts, int* offsets){
  if (threadIdx.x == 0){
    int s = 0;
    for (int j = 0; j < KC; ++j){ offsets[j] = s; s += counts[j]; }
    offsets[KC] = s;
  }
}

__global__ __launch_bounds__(256) void scatter_k(const int* __restrict__ Y, const int* __restrict__ offsets,
                                                 int* cursors, int* __restrict__ perm, int m){
  int i = blockIdx.x * 256 + threadIdx.x;
  if (i < m){
    int y = Y[i];
    if (y >= 0 && y < KC){
      int pos = offsets[y] + atomicAdd(&cursors[y], 1);
      perm[pos] = i;
    }
  }
}

// ---------------- per-class Gram (lower-triangle 64x64 tiles) ----------------
// grid: (36, KC). Block 256 = 16x16 threads, 4x4 outputs/thread.
__global__ __launch_bounds__(256) void gram_k(const float* __restrict__ X,
                                              const int* __restrict__ perm,
                                              const int* __restrict__ offsets,
                                              float* __restrict__ Gk){
  __shared__ float As[16][64];
  __shared__ float Bs[16][64];

  int cls = blockIdx.y;
  int ta = 0, rem = blockIdx.x;
  while (rem >= ta + 1){ rem -= ta + 1; ++ta; }
  int tb = rem;
  int a0 = ta * 64, b0 = tb * 64;
  bool diag = (ta == tb);

  int start = offsets[cls];
  int n = offsets[cls + 1] - start;

  int tid = threadIdx.x;
  int tx = tid & 15, ty = tid >> 4;

  float acc[4][4];
  #pragma unroll
  for (int i = 0; i < 4; ++i)
    #pragma unroll
    for (int j = 0; j < 4; ++j) acc[i][j] = 0.f;

  int c = tid & 63;
  int kb = tid >> 6;   // 0..3

  for (int r0 = 0; r0 < n; r0 += 16){
    #pragma unroll
    for (int it = 0; it < 4; ++it){
      int kk = it * 4 + kb;
      int r = r0 + kk;
      float va = 0.f, vb = 0.f;
      if (r < n){
        int row = perm[start + r];
        const float* xp = X + (long)row * P;
        va = xp[a0 + c];
        if (!diag) vb = xp[b0 + c];
      }
      As[kk][c] = va;
      if (!diag) Bs[kk][c] = vb;
    }
    __syncthreads();
    const float (*Bp)[64] = diag ? As : Bs;
    #pragma unroll
    for (int kk = 0; kk < 16; ++kk){
      float4 a4 = *(const float4*)&As[kk][ty * 4];
      float4 b4 = *(const float4*)&Bp[kk][tx * 4];
      float av[4] = {a4.x, a4.y, a4.z, a4.w};
      float bv[4] = {b4.x, b4.y, b4.z, b4.w};
      #pragma unroll
      for (int i = 0; i < 4; ++i)
        #pragma unroll
        for (int j = 0; j < 4; ++j)
          acc[i][j] += av[i] * bv[j];
    }
    __syncthreads();
  }

  float* C = Gk + (long)cls * P * P;
  #pragma unroll
  for (int i = 0; i < 4; ++i){
    int a = a0 + ty * 4 + i;
    #pragma unroll
    for (int j = 0; j < 4; ++j){
      int b = b0 + tx * 4 + j;
      C[a * P + b] = acc[i][j];
    }
  }
}

// ---------------- form A_j = I + s_j*Gk_j (in place, lower tri); slot 10 = I + scal*sum ----------------
__global__ __launch_bounds__(256) void formA_k(float* __restrict__ Gk, const int* __restrict__ counts, float m_tot){
  int idx = blockIdx.x * 256 + threadIdx.x;
  int r = idx >> 9, cc = idx & (P - 1);
  if (cc > r) return;
  long off = (long)r * P + cc;
  float diag = (r == cc) ? 1.f : 0.f;
  float g = 0.f;
  #pragma unroll
  for (int j = 0; j < KC; ++j){
    float v = Gk[(long)j * P * P + off];
    g += v;
    float trPi = (float)counts[j] + 1e-8f;
    float s = (float)P / (trPi * EPSV);
    Gk[(long)j * P * P + off] = diag + s * v;
  }
  float scal = (float)P / (m_tot * EPSV);
  Gk[(long)KC * P * P + off] = diag + scal * g;
}

// ---------------- panel factor: one block per matrix, registers, 1 barrier/col ----------------
// Factors cols j0..j0+NB-1 (rows j0..P-1), writes back rows >= j0+NB as L panel,
// atomically accumulates sum(log(pivot)) into logdets[matrix].
__global__ __launch_bounds__(256) void panel_k(float* __restrict__ Amats, float* __restrict__ logdets, int j0){
  __shared__ float prbuf[NB * NB];   // per-column broadcast slot (no WAR across cols)
  float* A = Amats + (long)blockIdx.x * P * P;
  int tid = threadIdx.x;
  int q = P - j0;
  int i1 = j0 + tid;
  int i2 = i1 + 256;
  bool has1 = (tid < q);
  bool has2 = (tid + 256 < q);
  float a1[NB], a2[NB];

  if (has1){
    const float* src = A + (long)i1 * P + j0;
    #pragma unroll
    for (int u = 0; u < NB; u += 4){
      float4 v = *(const float4*)(src + u);
      a1[u] = v.x; a1[u+1] = v.y; a1[u+2] = v.z; a1[u+3] = v.w;
    }
  }
  if (has2){
    const float* src = A + (long)i2 * P + j0;
    #pragma unroll
    for (int u = 0; u < NB; u += 4){
      float4 v = *(const float4*)(src + u);
      a2[u] = v.x; a2[u+1] = v.y; a2[u+2] = v.z; a2[u+3] = v.w;
    }
  }

  float logsum = 0.f;
  #pragma unroll
  for (int jj = 0; jj < NB; ++jj){
    if (tid < NB) prbuf[jj * NB + tid] = a1[jj];   // col jj of diag-block rows
    __syncthreads();
    float pr[NB];
    #pragma unroll
    for (int u = 0; u < NB; u += 4){
      float4 v = *(const float4*)&prbuf[jj * NB + u];
      pr[u] = v.x; pr[u+1] = v.y; pr[u+2] = v.z; pr[u+3] = v.w;
    }
    float d = pr[jj];
    if (tid == 0) logsum += logf(d);
    float inv = 1.0f / d;
    float rs = rsqrtf(d);
    if (has1 && tid >= jj){
      float w = a1[jj] * inv;
      #pragma unroll
      for (int l = 0; l < NB; ++l) if (l > jj) a1[l] -= w * pr[l];
      a1[jj] *= rs;
    }
    if (has2){
      float w = a2[jj] * inv;
      #pragma unroll
      for (int l = 0; l < NB; ++l) if (l > jj) a2[l] -= w * pr[l];
      a2[jj] *= rs;
    }
  }

  if (tid == 0) atomicAdd(&logdets[blockIdx.x], logsum);

  // store back only rows below the diag block (what syrk consumes)
  if (has1 && tid >= NB){
    float* dst = A + (long)i1 * P + j0;
    #pragma unroll
    for (int u = 0; u < NB; u += 4){
      float4 v = {a1[u], a1[u+1], a1[u+2], a1[u+3]};
      *(float4*)(dst + u) = v;
    }
  }
  if (has2){
    float* dst = A + (long)i2 * P + j0;
    #pragma unroll
    for (int u = 0; u < NB; u += 4){
      float4 v = {a2[u], a2[u+1], a2[u+2], a2[u+3]};
      *(float4*)(dst + u) = v;
    }
  }
}

// ---------------- trailing syrk: one 128x128 tile per block ----------------
// grid (ntile, KC+1). A[i][l] -= sum_u L[i][u]*L[l][u] for the block's tile.
__global__ __launch_bounds__(256) void syrk_k(float* __restrict__ Amats, int j0){
  __shared__ float La[128 * NB];
  __shared__ float Lb[128 * NB];
  int ta = 0, rem = blockIdx.x;
  while (rem >= ta + 1){ rem -= ta + 1; ++ta; }
  int tb = rem;
  int j1 = j0 + NB;
  int ti0 = j1 + ta * 128;
  int tl0 = j1 + tb * 128;
  float* A = Amats + (long)blockIdx.y * P * P;
  int tid = threadIdx.x;

  // stage both panel slabs, swizzled + zero-padded
  for (int idx = tid; idx < 128 * NB; idx += 256){
    int rr = idx >> 5;
    int u  = idx & 31;
    int sw = rr * NB + (u ^ (rr & 31));
    int i = ti0 + rr;
    La[sw] = (i < P) ? A[(long)i * P + j0 + u] : 0.f;
    int l = tl0 + rr;
    Lb[sw] = (l < P) ? A[(long)l * P + j0 + u] : 0.f;
  }
  __syncthreads();

  int tx = tid & 15, ty = tid >> 4;
  float acc[8][8];
  #pragma unroll
  for (int r = 0; r < 8; ++r)
    #pragma unroll
    for (int c2 = 0; c2 < 8; ++c2) acc[r][c2] = 0.f;

  for (int u = 0; u < NB; ++u){
    float a8[8], b8[8];
    #pragma unroll
    for (int r = 0; r < 8; ++r){
      int rr = ty + 16 * r;
      a8[r] = La[rr * NB + (u ^ (rr & 31))];
    }
    #pragma unroll
    for (int c2 = 0; c2 < 8; ++c2){
      int rr = tx + 16 * c2;
      b8[c2] = Lb[rr * NB + (u ^ (rr & 31))];
    }
    #pragma unroll
    for (int r = 0; r < 8; ++r)
      #pragma unroll
      for (int c2 = 0; c2 < 8; ++c2)
        acc[r][c2] += a8[r] * b8[c2];
  }

  #pragma unroll
  for (int r = 0; r < 8; ++r){
    int i = ti0 + ty + 16 * r;
    if (i >= P) continue;
    #pragma unroll
    for (int c2 = 0; c2 < 8; ++c2){
      int l = tl0 + tx + 16 * c2;
      if (l < P && l <= i)
        A[(long)i * P + l] -= acc[r][c2];
    }
  }
}

// ---------------- final reduction ----------------
__global__ __launch_bounds__(64) void final_k(const float* __restrict__ logdets,
                                              const int* __restrict__ counts,
                                              float* __restrict__ out, float m_tot){
  if (threadIdx.x == 0 && blockIdx.x == 0){
    out[0] = 0.5f * logdets[KC];
    float comp = 0.f;
    for (int j = 0; j < KC; ++j){
      float trPi = (float)counts[j] + 1e-8f;
      comp += logdets[j] * trPi / m_tot;
    }
    out[1] = 0.5f * comp;
  }
}

extern "C" void kernel_launch(void* const* d_in, const int* in_sizes, int n_in,
                              void* d_out, int out_size, void* d_ws, size_t ws_size,
                              hipStream_t stream) {
  (void)n_in; (void)out_size; (void)ws_size;
  const float* X = (const float*)d_in[0];
  const int*   Y = (const int*)d_in[1];
  int m = in_sizes[0] / P;     // 16384

  float* Gk      = (float*)d_ws;                 // 11 * P*P floats
  int*   perm    = (int*)(Gk + 11L * P * P);     // m ints
  int*   counts  = perm + m;                     // 16
  int*   cursors = counts + 16;                  // 16
  int*   offsets = cursors + 16;                 // 16
  float* logdets = (float*)(offsets + 16);       // 11

  meta_zero<<<1, 64, 0, stream>>>(counts, cursors, logdets);
  hist_k<<<(m + 255) / 256, 256, 0, stream>>>(Y, counts, m);
  offsets_k<<<1, 64, 0, stream>>>(counts, offsets);
  scatter_k<<<(m + 255) / 256, 256, 0, stream>>>(Y, offsets, cursors, perm, m);

  dim3 gg(36, KC);
  gram_k<<<gg, 256, 0, stream>>>(X, perm, offsets, Gk);

  formA_k<<<(P * P) / 256, 256, 0, stream>>>(Gk, counts, (float)m);

  // panel sweep: stream order provides the inter-phase device-wide sync
  for (int j0 = 0; j0 < P; j0 += NB){
    panel_k<<<KC + 1, 256, 0, stream>>>(Gk, logdets, j0);
    int q2 = P - j0 - NB;
    if (q2 > 0){
      int t = (q2 + 127) / 128;
      int ntile = t * (t + 1) / 2;
      dim3 sg(ntile, KC + 1);
      syrk_k<<<sg, 256, 0, stream>>>(Gk, j0);
    }
  }

  final_k<<<1, 64, 0, stream>>>(logdets, counts, (float*)d_out, (float)m);
}

// Round 5
// 1576.840 us; speedup vs baseline: 1.6012x; 1.1518x over previous
//
#include <hip/hip_runtime.h>
#include <math.h>

#define P 512
#define KC 10
#define NB 32
#define SS 4
#define EPSV 0.01f

// ---------------- init: zero Gram slots + metadata ----------------
__global__ __launch_bounds__(256) void init_k(float* __restrict__ Gk, int* __restrict__ meta){
  long n4 = 11L * P * P / 4;
  float4 z = {0.f, 0.f, 0.f, 0.f};
  for (long i = blockIdx.x * 256L + threadIdx.x; i < n4; i += (long)gridDim.x * 256)
    ((float4*)Gk)[i] = z;
  if (blockIdx.x == 0)
    for (int t = threadIdx.x; t < 304; t += 256) meta[t] = 0;   // counts16+offsets16+flags256+logdets16
}

// ---------------- fused histogram + scan + scatter (one block) ----------------
__global__ __launch_bounds__(256) void sort_k(const int* __restrict__ Y, int* __restrict__ perm,
                                              int* __restrict__ counts, int* __restrict__ offsets, int m){
  __shared__ int cnt[KC], off[KC + 1], cur[KC];
  int tid = threadIdx.x;
  if (tid < KC) cnt[tid] = 0;
  __syncthreads();
  for (int i = tid; i < m; i += 256){
    int y = Y[i];
    if (y >= 0 && y < KC) atomicAdd(&cnt[y], 1);
  }
  __syncthreads();
  if (tid == 0){
    int s = 0;
    for (int j = 0; j < KC; ++j){ off[j] = s; s += cnt[j]; }
    off[KC] = s;
  }
  __syncthreads();
  if (tid < KC){ cur[tid] = off[tid]; counts[tid] = cnt[tid]; offsets[tid] = off[tid]; }
  if (tid == KC) offsets[KC] = off[KC];
  __syncthreads();
  for (int i = tid; i < m; i += 256){
    int y = Y[i];
    if (y >= 0 && y < KC){
      int pos = atomicAdd(&cur[y], 1);
      perm[pos] = i;
    }
  }
}

// ---------------- per-class Gram, k-split, double-atomic (class slot + sum slot) ----------------
// grid: (36, KC, SS). Block 256 = 16x16 threads, 4x4 outputs/thread.
__global__ __launch_bounds__(256) void gram_k(const float* __restrict__ X,
                                              const int* __restrict__ perm,
                                              const int* __restrict__ offsets,
                                              float* __restrict__ Gk){
  __shared__ float As[16][64];
  __shared__ float Bs[16][64];

  int cls = blockIdx.y;
  int z = blockIdx.z;
  int ta = 0, rem = blockIdx.x;
  while (rem >= ta + 1){ rem -= ta + 1; ++ta; }
  int tb = rem;
  int a0 = ta * 64, b0 = tb * 64;
  bool diag = (ta == tb);

  int base = offsets[cls];
  int n_all = offsets[cls + 1] - base;
  int lo = (int)((long)n_all * z / SS);
  int hi = (int)((long)n_all * (z + 1) / SS);
  int start = base + lo;
  int n = hi - lo;

  int tid = threadIdx.x;
  int tx = tid & 15, ty = tid >> 4;

  float acc[4][4];
  #pragma unroll
  for (int i = 0; i < 4; ++i)
    #pragma unroll
    for (int j = 0; j < 4; ++j) acc[i][j] = 0.f;

  int c = tid & 63;
  int kb = tid >> 6;   // 0..3

  for (int r0 = 0; r0 < n; r0 += 16){
    #pragma unroll
    for (int it = 0; it < 4; ++it){
      int kk = it * 4 + kb;
      int r = r0 + kk;
      float va = 0.f, vb = 0.f;
      if (r < n){
        int row = perm[start + r];
        const float* xp = X + (long)row * P;
        va = xp[a0 + c];
        if (!diag) vb = xp[b0 + c];
      }
      As[kk][c] = va;
      if (!diag) Bs[kk][c] = vb;
    }
    __syncthreads();
    const float (*Bp)[64] = diag ? As : Bs;
    #pragma unroll
    for (int kk = 0; kk < 16; ++kk){
      float4 a4 = *(const float4*)&As[kk][ty * 4];
      float4 b4 = *(const float4*)&Bp[kk][tx * 4];
      float av[4] = {a4.x, a4.y, a4.z, a4.w};
      float bv[4] = {b4.x, b4.y, b4.z, b4.w};
      #pragma unroll
      for (int i = 0; i < 4; ++i)
        #pragma unroll
        for (int j = 0; j < 4; ++j)
          acc[i][j] += av[i] * bv[j];
    }
    __syncthreads();
  }

  float* C  = Gk + (long)cls * P * P;
  float* CS = Gk + (long)KC * P * P;
  #pragma unroll
  for (int i = 0; i < 4; ++i){
    int a = a0 + ty * 4 + i;
    #pragma unroll
    for (int j = 0; j < 4; ++j){
      int b = b0 + tx * 4 + j;
      atomicAdd(&C[a * P + b], acc[i][j]);
      atomicAdd(&CS[a * P + b], acc[i][j]);
    }
  }
}

// ---------------- dataflow Cholesky: one dispatch, flag-chained strips ----------------
// grid (16, 11). Block (p, mat) owns cols [32p,32p+32), rows >= 32p in registers.
// Applies panel s's rank-32 update when flags[mat*16+s] releases; factors; publishes.
__global__ __launch_bounds__(256) void chol_df(float* __restrict__ Gk,
                                               const int* __restrict__ counts,
                                               int* __restrict__ flags,
                                               float* __restrict__ logdets,
                                               float m_tot){
  __shared__ float Sb[NB * 36];   // stride 36: 16B-aligned float4 rows, broadcast reads
  int p   = blockIdx.x;
  int mat = blockIdx.y;
  int tid = threadIdx.x;
  float* A = Gk + (long)mat * P * P;
  int j0 = p * NB;
  int q  = P - j0;
  int i1 = j0 + tid;
  int i2 = i1 + 256;
  bool has1 = (tid < q);
  bool has2 = (tid + 256 < q);
  int fbase = mat * 16;

  float sc = (mat < KC) ? ((float)P / (((float)counts[mat] + 1e-8f) * EPSV))
                        : ((float)P / (m_tot * EPSV));

  // ---- load strip, inline formA transform (I + sc*G) ----
  float a1[NB], a2[NB];
  if (has1){
    const float* src = A + (long)i1 * P + j0;
    #pragma unroll
    for (int u = 0; u < NB; u += 4){
      float4 v = *(const float4*)(src + u);
      a1[u] = sc*v.x; a1[u+1] = sc*v.y; a1[u+2] = sc*v.z; a1[u+3] = sc*v.w;
    }
    if (tid < NB) a1[tid] += 1.0f;   // diagonal element of row i1 is col j0+tid
  }
  if (has2){
    const float* src = A + (long)i2 * P + j0;
    #pragma unroll
    for (int u = 0; u < NB; u += 4){
      float4 v = *(const float4*)(src + u);
      a2[u] = sc*v.x; a2[u+1] = sc*v.y; a2[u+2] = sc*v.z; a2[u+3] = sc*v.w;
    }
  }

  // ---- apply earlier panels as they are published ----
  for (int sp = 0; sp < p; ++sp){
    if (tid == 0){
      while (__hip_atomic_load(&flags[fbase + sp], __ATOMIC_ACQUIRE, __HIP_MEMORY_SCOPE_AGENT) == 0)
        __builtin_amdgcn_s_sleep(2);
    }
    __syncthreads();
    int jc = sp * NB;
    float lp1[NB], lp2[NB];
    if (has1){
      const float* src = A + (long)i1 * P + jc;
      #pragma unroll
      for (int u = 0; u < NB; u += 4){
        float4 v = *(const float4*)(src + u);
        lp1[u] = v.x; lp1[u+1] = v.y; lp1[u+2] = v.z; lp1[u+3] = v.w;
      }
    }
    if (has2){
      const float* src = A + (long)i2 * P + jc;
      #pragma unroll
      for (int u = 0; u < NB; u += 4){
        float4 v = *(const float4*)(src + u);
        lp2[u] = v.x; lp2[u+1] = v.y; lp2[u+2] = v.z; lp2[u+3] = v.w;
      }
    }
    // L rows [j0, j0+32) of this panel are exactly lp1 of threads 0..31
    if (tid < NB){
      #pragma unroll
      for (int u = 0; u < NB; ++u) Sb[u * 36 + tid] = lp1[u];
    }
    __syncthreads();
    for (int u = 0; u < NB; ++u){
      float w1 = has1 ? lp1[u] : 0.f;
      float w2 = has2 ? lp2[u] : 0.f;
      #pragma unroll
      for (int l4 = 0; l4 < NB; l4 += 4){
        float4 rv = *(const float4*)&Sb[u * 36 + l4];
        a1[l4+0] -= w1 * rv.x; a1[l4+1] -= w1 * rv.y;
        a1[l4+2] -= w1 * rv.z; a1[l4+3] -= w1 * rv.w;
        a2[l4+0] -= w2 * rv.x; a2[l4+1] -= w2 * rv.y;
        a2[l4+2] -= w2 * rv.z; a2[l4+3] -= w2 * rv.w;
      }
    }
    __syncthreads();
  }

  // ---- factor the strip: right-looking, registers, 1 barrier/col ----
  float logsum = 0.f;
  #pragma unroll
  for (int jj = 0; jj < NB; ++jj){
    if (tid < NB) Sb[jj * 36 + tid] = a1[jj];   // col jj of diag-block rows
    __syncthreads();
    float pr[NB];
    #pragma unroll
    for (int u = 0; u < NB; u += 4){
      float4 v = *(const float4*)&Sb[jj * 36 + u];
      pr[u] = v.x; pr[u+1] = v.y; pr[u+2] = v.z; pr[u+3] = v.w;
    }
    float d = pr[jj];
    if (tid == 0) logsum += logf(d);
    float inv = 1.0f / d;
    float rs = rsqrtf(d);
    if (has1 && tid >= jj){
      float w = a1[jj] * inv;
      #pragma unroll
      for (int l = 0; l < NB; ++l) if (l > jj) a1[l] -= w * pr[l];
      a1[jj] *= rs;
    }
    if (has2){
      float w = a2[jj] * inv;
      #pragma unroll
      for (int l = 0; l < NB; ++l) if (l > jj) a2[l] -= w * pr[l];
      a2[jj] *= rs;
    }
  }

  // ---- publish L rows >= j0+NB, release flag ----
  if (has1 && tid >= NB){
    float* dst = A + (long)i1 * P + j0;
    #pragma unroll
    for (int u = 0; u < NB; u += 4){
      float4 v = {a1[u], a1[u+1], a1[u+2], a1[u+3]};
      *(float4*)(dst + u) = v;
    }
  }
  if (has2){
    float* dst = A + (long)i2 * P + j0;
    #pragma unroll
    for (int u = 0; u < NB; u += 4){
      float4 v = {a2[u], a2[u+1], a2[u+2], a2[u+3]};
      *(float4*)(dst + u) = v;
    }
  }
  if (p < 15){
    __threadfence();
    __syncthreads();
    if (tid == 0)
      __hip_atomic_store(&flags[fbase + p], 1, __ATOMIC_RELEASE, __HIP_MEMORY_SCOPE_AGENT);
  }
  if (tid == 0) atomicAdd(&logdets[mat], logsum);
}

// ---------------- final reduction ----------------
__global__ __launch_bounds__(64) void final_k(const float* __restrict__ logdets,
                                              const int* __restrict__ counts,
                                              float* __restrict__ out, float m_tot){
  if (threadIdx.x == 0 && blockIdx.x == 0){
    out[0] = 0.5f * logdets[KC];
    float comp = 0.f;
    for (int j = 0; j < KC; ++j){
      float trPi = (float)counts[j] + 1e-8f;
      comp += logdets[j] * trPi / m_tot;
    }
    out[1] = 0.5f * comp;
  }
}

extern "C" void kernel_launch(void* const* d_in, const int* in_sizes, int n_in,
                              void* d_out, int out_size, void* d_ws, size_t ws_size,
                              hipStream_t stream) {
  (void)n_in; (void)out_size; (void)ws_size;
  const float* X = (const float*)d_in[0];
  const int*   Y = (const int*)d_in[1];
  int m = in_sizes[0] / P;     // 16384

  float* Gk      = (float*)d_ws;                 // 11 * P*P floats
  int*   perm    = (int*)(Gk + 11L * P * P);     // m ints
  int*   meta    = perm + m;                     // 304 ints, zeroed by init_k
  int*   counts  = meta;                         // 16
  int*   offsets = counts + 16;                  // 16
  int*   flags   = offsets + 16;                 // 256 (16x11 used)
  float* logdets = (float*)(flags + 256);        // 16

  init_k<<<512, 256, 0, stream>>>(Gk, meta);
  sort_k<<<1, 256, 0, stream>>>(Y, perm, counts, offsets, m);

  dim3 gg(36, KC, SS);
  gram_k<<<gg, 256, 0, stream>>>(X, perm, offsets, Gk);

  dim3 cg_(16, KC + 1);
  chol_df<<<cg_, 256, 0, stream>>>(Gk, counts, flags, logdets, (float)m);

  final_k<<<1, 64, 0, stream>>>(logdets, counts, (float*)d_out, (float)m);
}

// Round 6
// 653.160 us; speedup vs baseline: 3.8655x; 2.4142x over previous
//
#include <hip/hip_runtime.h>
#include <math.h>

#define P 512
#define KC 10
#define NB 32
#define SS 4
#define EPSV 0.01f
#define TR_ROWS 448

typedef __attribute__((ext_vector_type(8))) __bf16 bf16x8;
typedef __attribute__((ext_vector_type(4))) float floatx4;

// ---------------- init: zero Gram slots + metadata ----------------
__global__ __launch_bounds__(256) void init_k(float* __restrict__ Gk, int* __restrict__ meta){
  long n4 = 11L * P * P / 4;
  float4 z = {0.f, 0.f, 0.f, 0.f};
  for (long i = blockIdx.x * 256L + threadIdx.x; i < n4; i += (long)gridDim.x * 256)
    ((float4*)Gk)[i] = z;
  if (blockIdx.x == 0)
    for (int t = threadIdx.x; t < 304; t += 256) meta[t] = 0;
}

// ---------------- fused histogram + scan + scatter (one block) ----------------
__global__ __launch_bounds__(256) void sort_k(const int* __restrict__ Y, int* __restrict__ perm,
                                              int* __restrict__ counts, int* __restrict__ offsets, int m){
  __shared__ int cnt[KC], off[KC + 1], cur[KC];
  int tid = threadIdx.x;
  if (tid < KC) cnt[tid] = 0;
  __syncthreads();
  for (int i = tid; i < m; i += 256){
    int y = Y[i];
    if (y >= 0 && y < KC) atomicAdd(&cnt[y], 1);
  }
  __syncthreads();
  if (tid == 0){
    int s = 0;
    for (int j = 0; j < KC; ++j){ off[j] = s; s += cnt[j]; }
    off[KC] = s;
  }
  __syncthreads();
  if (tid < KC){ cur[tid] = off[tid]; counts[tid] = cnt[tid]; offsets[tid] = off[tid]; }
  if (tid == KC) offsets[KC] = off[KC];
  __syncthreads();
  for (int i = tid; i < m; i += 256){
    int y = Y[i];
    if (y >= 0 && y < KC){
      int pos = atomicAdd(&cur[y], 1);
      perm[pos] = i;
    }
  }
}

// ---------------- per-class Gram, k-split, double-atomic (class slot + sum slot) ----------------
__global__ __launch_bounds__(256) void gram_k(const float* __restrict__ X,
                                              const int* __restrict__ perm,
                                              const int* __restrict__ offsets,
                                              float* __restrict__ Gk){
  __shared__ float As[16][64];
  __shared__ float Bs[16][64];

  int cls = blockIdx.y;
  int z = blockIdx.z;
  int ta = 0, rem = blockIdx.x;
  while (rem >= ta + 1){ rem -= ta + 1; ++ta; }
  int tb = rem;
  int a0 = ta * 64, b0 = tb * 64;
  bool diag = (ta == tb);

  int base = offsets[cls];
  int n_all = offsets[cls + 1] - base;
  int lo = (int)((long)n_all * z / SS);
  int hi = (int)((long)n_all * (z + 1) / SS);
  int start = base + lo;
  int n = hi - lo;

  int tid = threadIdx.x;
  int tx = tid & 15, ty = tid >> 4;

  float acc[4][4];
  #pragma unroll
  for (int i = 0; i < 4; ++i)
    #pragma unroll
    for (int j = 0; j < 4; ++j) acc[i][j] = 0.f;

  int c = tid & 63;
  int kb = tid >> 6;

  for (int r0 = 0; r0 < n; r0 += 16){
    #pragma unroll
    for (int it = 0; it < 4; ++it){
      int kk = it * 4 + kb;
      int r = r0 + kk;
      float va = 0.f, vb = 0.f;
      if (r < n){
        int row = perm[start + r];
        const float* xp = X + (long)row * P;
        va = xp[a0 + c];
        if (!diag) vb = xp[b0 + c];
      }
      As[kk][c] = va;
      if (!diag) Bs[kk][c] = vb;
    }
    __syncthreads();
    const float (*Bp)[64] = diag ? As : Bs;
    #pragma unroll
    for (int kk = 0; kk < 16; ++kk){
      float4 a4 = *(const float4*)&As[kk][ty * 4];
      float4 b4 = *(const float4*)&Bp[kk][tx * 4];
      float av[4] = {a4.x, a4.y, a4.z, a4.w};
      float bv[4] = {b4.x, b4.y, b4.z, b4.w};
      #pragma unroll
      for (int i = 0; i < 4; ++i)
        #pragma unroll
        for (int j = 0; j < 4; ++j)
          acc[i][j] += av[i] * bv[j];
    }
    __syncthreads();
  }

  float* C  = Gk + (long)cls * P * P;
  float* CS = Gk + (long)KC * P * P;
  #pragma unroll
  for (int i = 0; i < 4; ++i){
    int a = a0 + ty * 4 + i;
    #pragma unroll
    for (int j = 0; j < 4; ++j){
      int b = b0 + tx * 4 + j;
      atomicAdd(&C[a * P + b], acc[i][j]);
      atomicAdd(&CS[a * P + b], acc[i][j]);
    }
  }
}

// ---------------- single-block-per-matrix MFMA Cholesky logdet ----------------
// 11 blocks x 1024 threads. Per 32-wide step: wave-0 register factor (shfl,
// no barriers), all-thread register trsm (uniform LDS reads), then trailing
// syrk via v_mfma_f32_16x16x32_bf16 with split-bf16 (hi/lo, 3 MFMAs).
// Matrix lives in global (L2-resident, 1 MB); panel L lives in LDS as bf16
// hi/lo with chunk-XOR swizzle. I + sc*G transform folded into first touch.
__global__ __launch_bounds__(1024) void chol_mfma(float* __restrict__ Gk,
                                                  const int* __restrict__ counts,
                                                  float* __restrict__ logdets,
                                                  float m_tot){
  __shared__ __bf16 Lhi[TR_ROWS * 32];
  __shared__ __bf16 Llo[TR_ROWS * 32];
  __shared__ float  Ld[NB * 33];
  __shared__ float  Ldr[NB];

  int mat  = blockIdx.x;
  int tid  = threadIdx.x;
  int lane = tid & 63;
  int wv   = tid >> 6;
  float* A = Gk + (long)mat * P * P;
  float sc = (mat < KC) ? ((float)P / (((float)counts[mat] + 1e-8f) * EPSV))
                        : ((float)P / (m_tot * EPSV));
  float logsum = 0.f;

  for (int s = 0; s < 16; ++s){
    int j0 = s * NB;
    int qt = P - j0 - NB;   // trailing rows below this panel's diag block

    // ---- wave 0: load + factor 32x32 diag block in registers (shfl) ----
    if (wv == 0){
      float a[NB];
      if (lane < NB){
        const float* src = A + (long)(j0 + lane) * P + j0;
        #pragma unroll
        for (int u = 0; u < NB; u += 4){
          float4 v = *(const float4*)(src + u);
          a[u] = v.x; a[u+1] = v.y; a[u+2] = v.z; a[u+3] = v.w;
        }
        if (s == 0){
          #pragma unroll
          for (int u = 0; u < NB; ++u) a[u] *= sc;
          a[lane] += 1.0f;
        }
      } else {
        #pragma unroll
        for (int u = 0; u < NB; ++u) a[u] = 0.f;
      }
      #pragma unroll
      for (int jj = 0; jj < NB; ++jj){
        float d = __shfl(a[jj], jj);
        if (lane == 0) logsum += logf(d);
        float inv = 1.0f / d;
        float rs  = rsqrtf(d);
        float w   = a[jj] * inv;
        #pragma unroll
        for (int l = 0; l < NB; ++l){
          if (l > jj){
            float prl = __shfl(a[l], jj);
            a[l] -= w * prl;
          }
        }
        a[jj] *= rs;
      }
      if (lane < NB){
        #pragma unroll
        for (int u = 0; u < NB; ++u) D:
        ;
      }
      if (lane < NB){
        #pragma unroll
        for (int u = 0; u < NB; ++u) Ld[lane * 33 + u] = a[u];
        Ldr[lane] = 1.0f / a[lane];
      }
    }
    __syncthreads();

    if (qt > 0){
      // ---- trsm: thread t owns row j0+NB+t; forward-solve vs Ld^T ----
      if (tid < qt){
        float b[NB];
        const float* src = A + (long)(j0 + NB + tid) * P + j0;
        #pragma unroll
        for (int u = 0; u < NB; u += 4){
          float4 v = *(const float4*)(src + u);
          b[u] = v.x; b[u+1] = v.y; b[u+2] = v.z; b[u+3] = v.w;
        }
        if (s == 0){
          #pragma unroll
          for (int u = 0; u < NB; ++u) b[u] *= sc;
        }
        #pragma unroll
        for (int jj = 0; jj < NB; ++jj){
          float acc = b[jj];
          for (int u = 0; u < jj; ++u) acc -= b[u] * Ld[jj * 33 + u];
          b[jj] = acc * Ldr[jj];
        }
        // write panel row as bf16 hi/lo, chunk-XOR swizzled (16B chunks)
        int t = tid;
        #pragma unroll
        for (int c = 0; c < 4; ++c){
          int sw = (t * 4 + (c ^ ((t >> 1) & 3))) * 8;
          bf16x8 vh, vl;
          #pragma unroll
          for (int j = 0; j < 8; ++j){
            float f = b[c * 8 + j];
            __bf16 h = (__bf16)f;
            vh[j] = h;
            vl[j] = (__bf16)(f - (float)h);
          }
          *(bf16x8*)&Lhi[sw] = vh;
          *(bf16x8*)&Llo[sw] = vl;
        }
      }
    }
    __syncthreads();

    if (qt > 0){
      // ---- trailing syrk: 32x32 tiles, lower-inclusive, one tile per wave-iter ----
      int tt = qt >> 5;
      int T  = tt * (tt + 1) / 2;
      int trail0 = j0 + NB;
      for (int idx = wv; idx < T; idx += 16){
        int ti = 0, rem = idx;
        while (rem >= ti + 1){ rem -= ti + 1; ++ti; }
        int tj = rem;
        int I0 = ti * 32, J0 = tj * 32;
        int c  = lane >> 4;

        bf16x8 ahi[2], alo[2], bhi[2], blo[2];
        #pragma unroll
        for (int h = 0; h < 2; ++h){
          int r1 = I0 + h * 16 + (lane & 15);
          int sw1 = (r1 * 4 + (c ^ ((r1 >> 1) & 3))) * 8;
          ahi[h] = *(const bf16x8*)&Lhi[sw1];
          alo[h] = *(const bf16x8*)&Llo[sw1];
          int r2 = J0 + h * 16 + (lane & 15);
          int sw2 = (r2 * 4 + (c ^ ((r2 >> 1) & 3))) * 8;
          bhi[h] = *(const bf16x8*)&Lhi[sw2];
          blo[h] = *(const bf16x8*)&Llo[sw2];
        }

        #pragma unroll
        for (int hi_ = 0; hi_ < 2; ++hi_){
          #pragma unroll
          for (int hj = 0; hj < 2; ++hj){
            floatx4 acc = {0.f, 0.f, 0.f, 0.f};
            acc = __builtin_amdgcn_mfma_f32_16x16x32_bf16(alo[hi_], bhi[hj], acc, 0, 0, 0);
            acc = __builtin_amdgcn_mfma_f32_16x16x32_bf16(ahi[hi_], blo[hj], acc, 0, 0, 0);
            acc = __builtin_amdgcn_mfma_f32_16x16x32_bf16(ahi[hi_], bhi[hj], acc, 0, 0, 0);
            // C/D layout (m89-verified): col = lane&15, row = (lane>>4)*4 + reg
            int grow0 = trail0 + I0 + hi_ * 16 + (lane >> 4) * 4;
            int gcol  = trail0 + J0 + hj  * 16 + (lane & 15);
            #pragma unroll
            for (int r = 0; r < 4; ++r){
              long off = (long)(grow0 + r) * P + gcol;
              float v = A[off];
              if (s == 0) v = sc * v + ((grow0 + r) == gcol ? 1.f : 0.f);
              A[off] = v - acc[r];
            }
          }
        }
      }
    }
    __syncthreads();
  }

  if (tid == 0) logdets[mat] = logsum;
}

// ---------------- final reduction ----------------
__global__ __launch_bounds__(64) void final_k(const float* __restrict__ logdets,
                                              const int* __restrict__ counts,
                                              float* __restrict__ out, float m_tot){
  if (threadIdx.x == 0 && blockIdx.x == 0){
    out[0] = 0.5f * logdets[KC];
    float comp = 0.f;
    for (int j = 0; j < KC; ++j){
      float trPi = (float)counts[j] + 1e-8f;
      comp += logdets[j] * trPi / m_tot;
    }
    out[1] = 0.5f * comp;
  }
}

extern "C" void kernel_launch(void* const* d_in, const int* in_sizes, int n_in,
                              void* d_out, int out_size, void* d_ws, size_t ws_size,
                              hipStream_t stream) {
  (void)n_in; (void)out_size; (void)ws_size;
  const float* X = (const float*)d_in[0];
  const int*   Y = (const int*)d_in[1];
  int m = in_sizes[0] / P;     // 16384

  float* Gk      = (float*)d_ws;                 // 11 * P*P floats
  int*   perm    = (int*)(Gk + 11L * P * P);     // m ints
  int*   meta    = perm + m;                     // 304 ints
  int*   counts  = meta;                         // 16
  int*   offsets = counts + 16;                  // 16
  int*   flags   = offsets + 16;                 // 256 (unused now)
  float* logdets = (float*)(flags + 256);        // 16

  init_k<<<512, 256, 0, stream>>>(Gk, meta);
  sort_k<<<1, 256, 0, stream>>>(Y, perm, counts, offsets, m);

  dim3 gg(36, KC, SS);
  gram_k<<<gg, 256, 0, stream>>>(X, perm, offsets, Gk);

  chol_mfma<<<KC + 1, 1024, 0, stream>>>(Gk, counts, logdets, (float)m);

  final_k<<<1, 64, 0, stream>>>(logdets, counts, (float*)d_out, (float)m);
}

// Round 7
// 499.284 us; speedup vs baseline: 5.0568x; 1.3082x over previous
//
#include <hip/hip_runtime.h>
#include <math.h>

#define P 512
#define KC 10
#define NB 32
#define EPSV 0.01f
#define TR_ROWS 448
#define XT 17024   // padded columns: 16384 + per-class 64-alignment (max 17014)

typedef __attribute__((ext_vector_type(8))) __bf16 bf16x8;
typedef __attribute__((ext_vector_type(4))) float floatx4;

// ---------------- fused histogram + padded offsets + colmap scatter (one block) ----------------
// colmap[i] = source sample index for padded column i, or -1 (zero pad).
__global__ __launch_bounds__(256) void sort_k(const int* __restrict__ Y, int* __restrict__ colmap,
                                              int* __restrict__ counts, int* __restrict__ off_pad, int m){
  __shared__ int cnt[KC], offp[KC + 1], cur[KC];
  int tid = threadIdx.x;
  if (tid < KC) cnt[tid] = 0;
  __syncthreads();
  for (int i = tid; i < m; i += 256){
    int y = Y[i];
    if (y >= 0 && y < KC) atomicAdd(&cnt[y], 1);
  }
  __syncthreads();
  if (tid == 0){
    int s = 0;
    for (int j = 0; j < KC; ++j){ offp[j] = s; s += ((cnt[j] + 63) >> 6) << 6; }
    offp[KC] = s;
  }
  __syncthreads();
  if (tid < KC){ cur[tid] = offp[tid]; counts[tid] = cnt[tid]; off_pad[tid] = offp[tid]; }
  if (tid == KC) off_pad[KC] = offp[KC];
  for (int i = tid; i < XT; i += 256) colmap[i] = -1;
  __syncthreads();
  for (int i = tid; i < m; i += 256){
    int y = Y[i];
    if (y >= 0 && y < KC){
      int pos = atomicAdd(&cur[y], 1);
      colmap[pos] = i;
    }
  }
}

// ---------------- transpose + split-bf16 convert: X[m][512] -> Xt_hi/lo[512][XT] ----------------
// grid (XT/64, 8). 64 cols x 64 feats per block via LDS tile.
__global__ __launch_bounds__(256) void xt_k(const float* __restrict__ X, const int* __restrict__ colmap,
                                            __bf16* __restrict__ Xhi, __bf16* __restrict__ Xlo){
  __shared__ float T[64][65];
  int c0 = blockIdx.x * 64;
  int f0 = blockIdx.y * 64;
  int tid = threadIdx.x;

  int j = tid >> 2;          // col within tile
  int piece = tid & 3;       // 16-feature piece
  int s = colmap[c0 + j];
  if (s >= 0){
    const float* src = X + (long)s * P + f0 + piece * 16;
    #pragma unroll
    for (int q = 0; q < 4; ++q){
      float4 v = *(const float4*)(src + q * 4);
      T[piece * 16 + q * 4 + 0][j] = v.x;
      T[piece * 16 + q * 4 + 1][j] = v.y;
      T[piece * 16 + q * 4 + 2][j] = v.z;
      T[piece * 16 + q * 4 + 3][j] = v.w;
    }
  } else {
    #pragma unroll
    for (int q = 0; q < 16; ++q) T[piece * 16 + q][j] = 0.f;
  }
  __syncthreads();

  int f = tid >> 2;
  int cp = (tid & 3) * 16;
  bf16x8 vh0, vl0, vh1, vl1;
  #pragma unroll
  for (int q = 0; q < 8; ++q){
    float x0 = T[f][cp + q];
    float x1 = T[f][cp + 8 + q];
    __bf16 h0 = (__bf16)x0, h1 = (__bf16)x1;
    vh0[q] = h0; vl0[q] = (__bf16)(x0 - (float)h0);
    vh1[q] = h1; vl1[q] = (__bf16)(x1 - (float)h1);
  }
  long base = (long)(f0 + f) * XT + c0 + cp;
  *(bf16x8*)&Xhi[base]     = vh0;
  *(bf16x8*)&Xhi[base + 8] = vh1;
  *(bf16x8*)&Xlo[base]     = vl0;
  *(bf16x8*)&Xlo[base + 8] = vl1;
}

// ---------------- per-class Gram via MFMA, split-bf16 ----------------
// grid (36, KC). Block 256 = 4 waves; wave w handles 32x32 quadrant (w>>1, w&1)
// of a 64x64 lower-wedge tile. Fragments straight from global (L2/L3-resident).
__global__ __launch_bounds__(256) void gram_mfma(const __bf16* __restrict__ Xhi,
                                                 const __bf16* __restrict__ Xlo,
                                                 const int* __restrict__ counts,
                                                 const int* __restrict__ off_pad,
                                                 float* __restrict__ Gk){
  int cls = blockIdx.y;
  int ta = 0, rem = blockIdx.x;
  while (rem >= ta + 1){ rem -= ta + 1; ++ta; }
  int tb = rem;
  int a0 = ta * 64, b0 = tb * 64;

  int tid  = threadIdx.x;
  int lane = tid & 63;
  int wv   = tid >> 6;
  int wrow = wv >> 1, wcol = wv & 1;
  int fr   = lane & 15;
  int quad = lane >> 4;

  int cs0     = off_pad[cls];
  int nchunks = (counts[cls] + 31) >> 5;

  long arow0 = (long)(a0 + wrow * 32 + fr) * XT;       // + r*16*XT
  long brow0 = (long)(b0 + wcol * 32 + fr) * XT;

  floatx4 acc[2][2];
  #pragma unroll
  for (int i = 0; i < 2; ++i)
    #pragma unroll
    for (int j = 0; j < 2; ++j) acc[i][j] = (floatx4){0.f, 0.f, 0.f, 0.f};

  for (int ch = 0; ch < nchunks; ++ch){
    long co = cs0 + ch * 32 + quad * 8;
    bf16x8 ah[2], al[2], bh[2], bl[2];
    #pragma unroll
    for (int r = 0; r < 2; ++r){
      ah[r] = *(const bf16x8*)&Xhi[arow0 + (long)r * 16 * XT + co];
      al[r] = *(const bf16x8*)&Xlo[arow0 + (long)r * 16 * XT + co];
      bh[r] = *(const bf16x8*)&Xhi[brow0 + (long)r * 16 * XT + co];
      bl[r] = *(const bf16x8*)&Xlo[brow0 + (long)r * 16 * XT + co];
    }
    #pragma unroll
    for (int ri = 0; ri < 2; ++ri)
      #pragma unroll
      for (int rj = 0; rj < 2; ++rj){
        acc[ri][rj] = __builtin_amdgcn_mfma_f32_16x16x32_bf16(al[ri], bh[rj], acc[ri][rj], 0, 0, 0);
        acc[ri][rj] = __builtin_amdgcn_mfma_f32_16x16x32_bf16(ah[ri], bl[rj], acc[ri][rj], 0, 0, 0);
        acc[ri][rj] = __builtin_amdgcn_mfma_f32_16x16x32_bf16(ah[ri], bh[rj], acc[ri][rj], 0, 0, 0);
      }
  }

  // C/D layout: col = lane&15, row = (lane>>4)*4 + reg (m89-verified)
  float* C = Gk + (long)cls * P * P;
  #pragma unroll
  for (int ri = 0; ri < 2; ++ri){
    int a = a0 + wrow * 32 + ri * 16 + (lane >> 4) * 4;
    #pragma unroll
    for (int rj = 0; rj < 2; ++rj){
      int b = b0 + wcol * 32 + rj * 16 + (lane & 15);
      #pragma unroll
      for (int r = 0; r < 4; ++r)
        C[(long)(a + r) * P + b] = acc[ri][rj][r];
    }
  }
}

// ---------------- slot 10 = sum of class Grams ----------------
__global__ __launch_bounds__(256) void sum10_k(float* __restrict__ Gk){
  long i = (long)blockIdx.x * 256 + threadIdx.x;   // float4 index, P*P/4 total
  float4 s = {0.f, 0.f, 0.f, 0.f};
  #pragma unroll
  for (int j = 0; j < KC; ++j){
    float4 v = ((const float4*)(Gk + (long)j * P * P))[i];
    s.x += v.x; s.y += v.y; s.z += v.z; s.w += v.w;
  }
  ((float4*)(Gk + (long)KC * P * P))[i] = s;
}

// ---------------- single-block-per-matrix MFMA Cholesky logdet (R6, proven) ----------------
__global__ __launch_bounds__(1024) void chol_mfma(float* __restrict__ Gk,
                                                  const int* __restrict__ counts,
                                                  float* __restrict__ logdets,
                                                  float m_tot){
  __shared__ __bf16 Lhi[TR_ROWS * 32];
  __shared__ __bf16 Llo[TR_ROWS * 32];
  __shared__ float  Ld[NB * 33];
  __shared__ float  Ldr[NB];

  int mat  = blockIdx.x;
  int tid  = threadIdx.x;
  int lane = tid & 63;
  int wv   = tid >> 6;
  float* A = Gk + (long)mat * P * P;
  float sc = (mat < KC) ? ((float)P / (((float)counts[mat] + 1e-8f) * EPSV))
                        : ((float)P / (m_tot * EPSV));
  float logsum = 0.f;

  for (int s = 0; s < 16; ++s){
    int j0 = s * NB;
    int qt = P - j0 - NB;

    if (wv == 0){
      float a[NB];
      if (lane < NB){
        const float* src = A + (long)(j0 + lane) * P + j0;
        #pragma unroll
        for (int u = 0; u < NB; u += 4){
          float4 v = *(const float4*)(src + u);
          a[u] = v.x; a[u+1] = v.y; a[u+2] = v.z; a[u+3] = v.w;
        }
        if (s == 0){
          #pragma unroll
          for (int u = 0; u < NB; ++u) a[u] *= sc;
          a[lane] += 1.0f;
        }
      } else {
        #pragma unroll
        for (int u = 0; u < NB; ++u) a[u] = 0.f;
      }
      #pragma unroll
      for (int jj = 0; jj < NB; ++jj){
        float d = __shfl(a[jj], jj);
        if (lane == 0) logsum += logf(d);
        float inv = 1.0f / d;
        float rs  = rsqrtf(d);
        float w   = a[jj] * inv;
        #pragma unroll
        for (int l = 0; l < NB; ++l){
          if (l > jj){
            float prl = __shfl(a[l], jj);
            a[l] -= w * prl;
          }
        }
        a[jj] *= rs;
      }
      if (lane < NB){
        #pragma unroll
        for (int u = 0; u < NB; ++u) Ld[lane * 33 + u] = a[u];
        Ldr[lane] = 1.0f / a[lane];
      }
    }
    __syncthreads();

    if (qt > 0){
      if (tid < qt){
        float b[NB];
        const float* src = A + (long)(j0 + NB + tid) * P + j0;
        #pragma unroll
        for (int u = 0; u < NB; u += 4){
          float4 v = *(const float4*)(src + u);
          b[u] = v.x; b[u+1] = v.y; b[u+2] = v.z; b[u+3] = v.w;
        }
        if (s == 0){
          #pragma unroll
          for (int u = 0; u < NB; ++u) b[u] *= sc;
        }
        #pragma unroll
        for (int jj = 0; jj < NB; ++jj){
          float acc = b[jj];
          for (int u = 0; u < jj; ++u) acc -= b[u] * Ld[jj * 33 + u];
          b[jj] = acc * Ldr[jj];
        }
        int t = tid;
        #pragma unroll
        for (int c = 0; c < 4; ++c){
          int sw = (t * 4 + (c ^ ((t >> 1) & 3))) * 8;
          bf16x8 vh, vl;
          #pragma unroll
          for (int j = 0; j < 8; ++j){
            float f = b[c * 8 + j];
            __bf16 h = (__bf16)f;
            vh[j] = h;
            vl[j] = (__bf16)(f - (float)h);
          }
          *(bf16x8*)&Lhi[sw] = vh;
          *(bf16x8*)&Llo[sw] = vl;
        }
      }
    }
    __syncthreads();

    if (qt > 0){
      int tt = qt >> 5;
      int T  = tt * (tt + 1) / 2;
      int trail0 = j0 + NB;
      for (int idx = wv; idx < T; idx += 16){
        int ti = 0, rem = idx;
        while (rem >= ti + 1){ rem -= ti + 1; ++ti; }
        int tj = rem;
        int I0 = ti * 32, J0 = tj * 32;
        int c  = lane >> 4;

        bf16x8 ahi[2], alo[2], bhi[2], blo[2];
        #pragma unroll
        for (int h = 0; h < 2; ++h){
          int r1 = I0 + h * 16 + (lane & 15);
          int sw1 = (r1 * 4 + (c ^ ((r1 >> 1) & 3))) * 8;
          ahi[h] = *(const bf16x8*)&Lhi[sw1];
          alo[h] = *(const bf16x8*)&Llo[sw1];
          int r2 = J0 + h * 16 + (lane & 15);
          int sw2 = (r2 * 4 + (c ^ ((r2 >> 1) & 3))) * 8;
          bhi[h] = *(const bf16x8*)&Lhi[sw2];
          blo[h] = *(const bf16x8*)&Llo[sw2];
        }

        #pragma unroll
        for (int hi_ = 0; hi_ < 2; ++hi_){
          #pragma unroll
          for (int hj = 0; hj < 2; ++hj){
            floatx4 acc = {0.f, 0.f, 0.f, 0.f};
            acc = __builtin_amdgcn_mfma_f32_16x16x32_bf16(alo[hi_], bhi[hj], acc, 0, 0, 0);
            acc = __builtin_amdgcn_mfma_f32_16x16x32_bf16(ahi[hi_], blo[hj], acc, 0, 0, 0);
            acc = __builtin_amdgcn_mfma_f32_16x16x32_bf16(ahi[hi_], bhi[hj], acc, 0, 0, 0);
            int grow0 = trail0 + I0 + hi_ * 16 + (lane >> 4) * 4;
            int gcol  = trail0 + J0 + hj  * 16 + (lane & 15);
            #pragma unroll
            for (int r = 0; r < 4; ++r){
              long off = (long)(grow0 + r) * P + gcol;
              float v = A[off];
              if (s == 0) v = sc * v + ((grow0 + r) == gcol ? 1.f : 0.f);
              A[off] = v - acc[r];
            }
          }
        }
      }
    }
    __syncthreads();
  }

  if (tid == 0) logdets[mat] = logsum;
}

// ---------------- final reduction ----------------
__global__ __launch_bounds__(64) void final_k(const float* __restrict__ logdets,
                                              const int* __restrict__ counts,
                                              float* __restrict__ out, float m_tot){
  if (threadIdx.x == 0 && blockIdx.x == 0){
    out[0] = 0.5f * logdets[KC];
    float comp = 0.f;
    for (int j = 0; j < KC; ++j){
      float trPi = (float)counts[j] + 1e-8f;
      comp += logdets[j] * trPi / m_tot;
    }
    out[1] = 0.5f * comp;
  }
}

extern "C" void kernel_launch(void* const* d_in, const int* in_sizes, int n_in,
                              void* d_out, int out_size, void* d_ws, size_t ws_size,
                              hipStream_t stream) {
  (void)n_in; (void)out_size; (void)ws_size;
  const float* X = (const float*)d_in[0];
  const int*   Y = (const int*)d_in[1];
  int m = in_sizes[0] / P;     // 16384

  float*  Gk      = (float*)d_ws;                    // 11 * P*P floats (11 MB)
  __bf16* Xhi     = (__bf16*)(Gk + 11L * P * P);     // 512*XT bf16 (17.4 MB)
  __bf16* Xlo     = Xhi + (long)P * XT;              // 512*XT bf16
  int*    colmap  = (int*)(Xlo + (long)P * XT);      // XT ints
  int*    counts  = colmap + XT;                     // 16
  int*    off_pad = counts + 16;                     // 17
  float*  logdets = (float*)(off_pad + 17);          // 16

  sort_k<<<1, 256, 0, stream>>>(Y, colmap, counts, off_pad, m);

  dim3 xg(XT / 64, 8);
  xt_k<<<xg, 256, 0, stream>>>(X, colmap, Xhi, Xlo);

  dim3 gg(36, KC);
  gram_mfma<<<gg, 256, 0, stream>>>(Xhi, Xlo, counts, off_pad, Gk);

  sum10_k<<<P * P / 1024, 256, 0, stream>>>(Gk);

  chol_mfma<<<KC + 1, 1024, 0, stream>>>(Gk, counts, logdets, (float)m);

  final_k<<<1, 64, 0, stream>>>(logdets, counts, (float*)d_out, (float)m);
}